// Round 2
// baseline (769.827 us; speedup 1.0000x reference)
//
#include <hip/hip_runtime.h>
#include <hip/hip_bf16.h>
#include <cstdint>
#include <cstddef>

typedef __attribute__((ext_vector_type(8))) short short8;
typedef __attribute__((ext_vector_type(4))) short short4v;
typedef __attribute__((ext_vector_type(4))) float float4v;

#define S_LEN 2048
#define NHEADS 16
#define DHEAD 128

__device__ __forceinline__ short f2bf(float f) {
    union { float f; unsigned u; } v; v.f = f;
    unsigned r = (v.u + 0x7fffu + ((v.u >> 16) & 1u)) >> 16;
    return (short)(r & 0xffffu);
}

typedef __attribute__((address_space(1))) void gvoid;
typedef __attribute__((address_space(3))) void lvoid;

__device__ __forceinline__ void gl_lds16(const void* g, void* l) {
    __builtin_amdgcn_global_load_lds((gvoid*)g, (lvoid*)l, 16, 0, 0);
}

__device__ __forceinline__ float4v mfma16(short8 a, short8 b, float4v c) {
    return __builtin_amdgcn_mfma_f32_16x16x32_bf16(a, b, c, 0, 0, 0);
}

// swizzled LDS tile addressing: tiles are arrays of 16B chunks.
// 8-chunk rows (64 bf16/row):  chunk slot = row*8  + (ch ^ (row&7))
// 16-chunk rows (128 bf16/row): chunk slot = row*16 + (ch ^ (row&15))
__device__ __forceinline__ const char* lds8(const short* base, int row, int ch) {
    return (const char*)base + (((row << 3) + (ch ^ (row & 7))) << 4);
}
__device__ __forceinline__ const char* lds16a(const short* base, int row, int ch) {
    return (const char*)base + (((row << 4) + (ch ^ (row & 15))) << 4);
}

// ---------------- elementwise fp32 -> bf16 ----------------
__global__ __launch_bounds__(256)
void cvt_bf16(const float* __restrict__ X, short* __restrict__ Y) {
    size_t i = ((size_t)blockIdx.x * 256 + threadIdx.x) * 4;
    float4v v = *(const float4v*)(X + i);
    short4v o;
#pragma unroll
    for (int j = 0; j < 4; ++j) o[j] = f2bf(v[j]);
    *(short4v*)(Y + i) = o;
}

// ---------------- W[K][N] fp32 -> Wt[N][K] bf16 ----------------
__global__ __launch_bounds__(256)
void tposew(const float* __restrict__ W, short* __restrict__ Wt, int K, int N) {
    __shared__ float t[32][33];
    int bx = blockIdx.x, by = blockIdx.y;
    int tx = threadIdx.x & 31, ty = threadIdx.x >> 5;
#pragma unroll
    for (int i = 0; i < 32; i += 8)
        t[ty + i][tx] = W[(size_t)(by * 32 + ty + i) * N + bx * 32 + tx];
    __syncthreads();
#pragma unroll
    for (int i = 0; i < 32; i += 8)
        Wt[(size_t)(bx * 32 + ty + i) * K + by * 32 + tx] = f2bf(t[tx][ty + i]);
}

// ---------------- BT-GEMM: C[M][N] = A[M][K] * Bt[N][K]^T (bf16 in, f32 acc) ----
// MODE 0: store bf16 row-major; MODE 1: store f32 row-major;
// MODE 2: store bf16 scattered as Vt[b][n][s] (n = h*128+dh), i.e. ((b*2048+n)*2048 + s)
template <int MODE>
__global__ __launch_bounds__(256, 2)
void gemm_bt(const short* __restrict__ A, const short* __restrict__ Bt,
             void* __restrict__ Cv, int M, int N, int K) {
    __shared__ short sA[128 * 64];
    __shared__ short sB[128 * 64];
    const int tid = threadIdx.x;
    const int wid = tid >> 6, lane = tid & 63;
    const int quad = lane >> 4, l15 = lane & 15;
    const int n0 = blockIdx.x * 128, m0 = blockIdx.y * 128;
    const int wm = (wid & 1) * 64, wn = (wid >> 1) * 64;
    float4v acc[4][4] = {};
    for (int k0 = 0; k0 < K; k0 += 64) {
        __syncthreads();
#pragma unroll
        for (int i = 0; i < 4; ++i) {
            int c = i * 256 + tid;
            int row = c >> 3, kc = c & 7, g = kc ^ (row & 7);
            int lb = ((i << 8) + (wid << 6)) << 4;
            gl_lds16(A + (size_t)(m0 + row) * K + k0 + g * 8, (char*)(void*)sA + lb);
            gl_lds16(Bt + (size_t)(n0 + row) * K + k0 + g * 8, (char*)(void*)sB + lb);
        }
        __syncthreads();
#pragma unroll
        for (int ks = 0; ks < 2; ++ks) {
            short8 af[4], bf[4];
#pragma unroll
            for (int t = 0; t < 4; ++t) {
                int q = ks * 4 + quad;
                af[t] = *(const short8*)lds8(sA, wm + t * 16 + l15, q);
                bf[t] = *(const short8*)lds8(sB, wn + t * 16 + l15, q);
            }
#pragma unroll
            for (int mt = 0; mt < 4; ++mt)
#pragma unroll
                for (int nt = 0; nt < 4; ++nt)
                    acc[mt][nt] = mfma16(af[mt], bf[nt], acc[mt][nt]);
        }
    }
#pragma unroll
    for (int mt = 0; mt < 4; ++mt)
#pragma unroll
        for (int nt = 0; nt < 4; ++nt) {
            int rbase = m0 + wm + mt * 16 + quad * 4;
            int col = n0 + wn + nt * 16 + l15;
            if (MODE == 0) {
                short* Cb = (short*)Cv;
#pragma unroll
                for (int i = 0; i < 4; ++i)
                    Cb[(size_t)(rbase + i) * N + col] = f2bf(acc[mt][nt][i]);
            } else if (MODE == 1) {
                float* Cf = (float*)Cv;
#pragma unroll
                for (int i = 0; i < 4; ++i)
                    Cf[(size_t)(rbase + i) * N + col] = acc[mt][nt][i];
            } else {
                short4v pk;
#pragma unroll
                for (int i = 0; i < 4; ++i) pk[i] = f2bf(acc[mt][nt][i]);
                int bb = rbase >> 11, s = rbase & 2047;
                short* Cb = (short*)Cv;
                *(short4v*)(Cb + ((size_t)(bb * 2048 + col) * 2048 + s)) = pk;
            }
        }
}

// ---------------- fused differential attention (v2: 64 q-rows/WG, 4 WG/CU) -----
// Q,Kq: bf16 [4096][4096] (col = h*256 + split*128 + dh)
// Vt:   bf16 [B][NH][DH][S]
// AO:   f32  [4096][2048]
__global__ __launch_bounds__(256, 4)
void attn_kernel(const short* __restrict__ Q, const short* __restrict__ Kq,
                 const short* __restrict__ Vt, const float* __restrict__ lam,
                 float* __restrict__ AO) {
    __shared__ short sK[64 * 128];    // 16 KB: K-split tile, 16-chunk rows
    __shared__ short sV[64 * 128];    // 16 KB: pass1 = K2 tile (16-chunk); pass2 = V tile (8-chunk)
    __shared__ short sP[4][16 * 64];  // 2 KB / wave, 8-chunk rows

    const int tid = threadIdx.x;
    const int wid = tid >> 6, lane = tid & 63;
    const int quad = lane >> 4, l15 = lane & 15;

    // XCD swizzle: all 32 q-blocks of one (b,h) land on one XCD -> K panel L2-resident
    const int xb = blockIdx.x;
    const int j = xb >> 3;
    const int bh = (xb & 7) * 4 + (j >> 5);
    const int qx = j & 31;
    const int b = bh >> 4, h = bh & 15;
    const int wrow = qx * 64 + wid * 16;

    const float lamh = lam[h];
    const float KC = 0.12752965f;  // (1/sqrt(128)) * log2(e)
    const float L2E = 1.4426950408889634f;

    short8 q1f[4], q2f[4];
    {
        const short* qb = Q + (size_t)(b * S_LEN + wrow + l15) * 4096 + h * 256 + quad * 8;
#pragma unroll
        for (int ks = 0; ks < 4; ++ks) {
            q1f[ks] = *(const short8*)(qb + ks * 32);
            q2f[ks] = *(const short8*)(qb + ks * 32 + 128);
        }
    }
    const short* k1g = Kq + (size_t)(b * S_LEN) * 4096 + h * 256;
    const short* k2g = k1g + 128;
    const short* vg = Vt + (size_t)(b * NHEADS + h) * DHEAD * S_LEN;

    int offK[4], offV[4], lbs[4];
#pragma unroll
    for (int i = 0; i < 4; ++i) {
        int c = i * 256 + tid;
        int row = c >> 4, kc = c & 15;
        offK[i] = row * 4096 + ((kc ^ (row & 15)) << 3);
        int dh = c >> 3, vc = c & 7;
        offV[i] = dh * 2048 + ((vc ^ (dh & 7)) << 3);
        lbs[i] = ((i << 8) + (wid << 6)) << 4;
    }

    float l1a[4] = {}, l2a[4] = {};

    // ---- pass 1: l1 = sum exp2(s1*KC), l2 = sum exp2(s2*KC); no max needed (|s|<~5)
    for (int kt = 0; kt < S_LEN; kt += 64) {
        const short* k1b = k1g + (size_t)kt * 4096;
        const short* k2b = k2g + (size_t)kt * 4096;
        __syncthreads();
#pragma unroll
        for (int i = 0; i < 4; ++i) {
            gl_lds16(k1b + offK[i], (char*)(void*)sK + lbs[i]);
            gl_lds16(k2b + offK[i], (char*)(void*)sV + lbs[i]);
        }
        __syncthreads();
#pragma unroll
        for (int nt = 0; nt < 4; ++nt) {
            float4v s1 = {}, s2 = {};
            int krow = nt * 16 + l15;
#pragma unroll
            for (int ks = 0; ks < 4; ++ks) {
                int q = ks * 4 + quad;
                s1 = mfma16(q1f[ks], *(const short8*)lds16a(sK, krow, q), s1);
                s2 = mfma16(q2f[ks], *(const short8*)lds16a(sV, krow, q), s2);
            }
#pragma unroll
            for (int r = 0; r < 4; ++r) {
                l1a[r] += __builtin_amdgcn_exp2f(s1[r] * KC);
                l2a[r] += __builtin_amdgcn_exp2f(s2[r] * KC);
            }
        }
    }
#pragma unroll
    for (int off = 1; off < 16; off <<= 1)
#pragma unroll
        for (int r = 0; r < 4; ++r) {
            l1a[r] += __shfl_xor(l1a[r], off, 64);
            l2a[r] += __shfl_xor(l2a[r], off, 64);
        }
    float il1[4], il2[4];
#pragma unroll
    for (int r = 0; r < 4; ++r) {
        il1[r] = L2E / l1a[r];            // p1*log2e = t1*il1
        il2[r] = (L2E * lamh) / l2a[r];   // lam*p2*log2e = t2*il2
    }

    float lda[4] = {};
    float4v oacc[8] = {};

    // ---- pass 2: e = exp(p1 - lam*p2) = exp2(t1*il1 - t2*il2); O += P@V
    for (int kt = 0; kt < S_LEN; kt += 64) {
        const short* k1b = k1g + (size_t)kt * 4096;
        const short* k2b = k2g + (size_t)kt * 4096;
        const short* vb = vg + kt;
        __syncthreads();
#pragma unroll
        for (int i = 0; i < 4; ++i) {
            gl_lds16(k1b + offK[i], (char*)(void*)sK + lbs[i]);
            gl_lds16(vb + offV[i], (char*)(void*)sV + lbs[i]);
        }
        __syncthreads();
        float4v s1[4];
#pragma unroll
        for (int nt = 0; nt < 4; ++nt) {
            s1[nt] = (float4v){0.f, 0.f, 0.f, 0.f};
            int krow = nt * 16 + l15;
#pragma unroll
            for (int ks = 0; ks < 4; ++ks)
                s1[nt] = mfma16(q1f[ks], *(const short8*)lds16a(sK, krow, ks * 4 + quad), s1[nt]);
        }
        __syncthreads();   // all waves done reading K1 tile
#pragma unroll
        for (int i = 0; i < 4; ++i)
            gl_lds16(k2b + offK[i], (char*)(void*)sK + lbs[i]);
        __syncthreads();
        short* sPw = sP[wid];
#pragma unroll
        for (int nt = 0; nt < 4; ++nt) {
            float4v s2 = {};
            int krow = nt * 16 + l15;
#pragma unroll
            for (int ks = 0; ks < 4; ++ks)
                s2 = mfma16(q2f[ks], *(const short8*)lds16a(sK, krow, ks * 4 + quad), s2);
#pragma unroll
            for (int r = 0; r < 4; ++r) {
                float t1 = __builtin_amdgcn_exp2f(s1[nt][r] * KC);
                float t2 = __builtin_amdgcn_exp2f(s2[r] * KC);
                float e = __builtin_amdgcn_exp2f(t1 * il1[r] - t2 * il2[r]);
                lda[r] += e;
                int qrow = quad * 4 + r;
                int key = nt * 16 + l15;
                *(short*)((char*)sPw +
                          ((((qrow << 3) + ((key >> 3) ^ (qrow & 7))) << 4) +
                           ((key & 7) << 1))) = f2bf(e);
            }
        }
        // PV: sP is wave-private (lgkmcnt suffices, no barrier); sV protected by loop-top sync
#pragma unroll
        for (int kk = 0; kk < 2; ++kk) {
            short8 pa = *(const short8*)lds8(sPw, l15, kk * 4 + quad);
#pragma unroll
            for (int nt = 0; nt < 8; ++nt)
                oacc[nt] = mfma16(pa, *(const short8*)lds8(sV, nt * 16 + l15, kk * 4 + quad), oacc[nt]);
        }
    }
#pragma unroll
    for (int off = 1; off < 16; off <<= 1)
#pragma unroll
        for (int r = 0; r < 4; ++r)
            lda[r] += __shfl_xor(lda[r], off, 64);
    float ild[4];
#pragma unroll
    for (int r = 0; r < 4; ++r) ild[r] = 1.0f / lda[r];
    const int rowb = b * S_LEN + wrow + quad * 4;
#pragma unroll
    for (int nt = 0; nt < 8; ++nt) {
        int col = h * DHEAD + nt * 16 + l15;
#pragma unroll
        for (int r = 0; r < 4; ++r)
            AO[(size_t)(rowb + r) * 2048 + col] = oacc[nt][r] * ild[r];
    }
}

// ---------------- RMS norm + scale * (1 - mean(lam)), f32 -> bf16 ----------------
__global__ __launch_bounds__(256)
void rms_kernel(const float* __restrict__ AO, const float* __restrict__ gs,
                const float* __restrict__ lam, short* __restrict__ Y) {
    int row = blockIdx.x, tid = threadIdx.x;
    const float* x = AO + (size_t)row * 2048;
    float4v v0 = *(const float4v*)(x + tid * 8);
    float4v v1 = *(const float4v*)(x + tid * 8 + 4);
    float ss = 0;
#pragma unroll
    for (int j = 0; j < 4; ++j) ss += v0[j] * v0[j] + v1[j] * v1[j];
#pragma unroll
    for (int off = 32; off > 0; off >>= 1) ss += __shfl_xor(ss, off, 64);
    __shared__ float wsum[4];
    if ((tid & 63) == 0) wsum[tid >> 6] = ss;
    __syncthreads();
    float tot = wsum[0] + wsum[1] + wsum[2] + wsum[3];
    float lm = 0;
#pragma unroll
    for (int i = 0; i < 16; ++i) lm += lam[i];
    float f = (1.0f - lm * (1.0f / 16.0f)) * rsqrtf(tot * (1.0f / 2048.0f) + 1e-6f);
    float4v g0 = *(const float4v*)(gs + tid * 8);
    float4v g1 = *(const float4v*)(gs + tid * 8 + 4);
    short4v o0, o1;
#pragma unroll
    for (int j = 0; j < 4; ++j) {
        o0[j] = f2bf(v0[j] * f * g0[j]);
        o1[j] = f2bf(v1[j] * f * g1[j]);
    }
    *(short4v*)(Y + (size_t)row * 2048 + tid * 8) = o0;
    *(short4v*)(Y + (size_t)row * 2048 + tid * 8 + 4) = o1;
}

extern "C" void kernel_launch(void* const* d_in, const int* in_sizes, int n_in,
                              void* d_out, int out_size, void* d_ws, size_t ws_size,
                              hipStream_t stream) {
    const float* x = (const float*)d_in[0];
    const float* Wq = (const float*)d_in[1];
    const float* Wk = (const float*)d_in[2];
    const float* Wv = (const float*)d_in[3];
    const float* Wo = (const float*)d_in[4];
    const float* nsc = (const float*)d_in[5];
    const float* lam = (const float*)d_in[6];
    float* out = (float*)d_out;
    (void)in_sizes; (void)n_in; (void)out_size; (void)ws_size;

    char* ws = (char*)d_ws;
    short* Xb  = (short*)(ws);                 // 16 MiB  [4096][2048]
    short* Wqt = (short*)(ws + 16777216);      // 16 MiB  [4096][2048]
    short* Wkt = (short*)(ws + 33554432);      // 16 MiB  [4096][2048]
    short* Wvt = (short*)(ws + 50331648);      //  8 MiB  [2048][2048]
    short* Wot = (short*)(ws + 58720256);      //  8 MiB  [2048][2048]
    short* Cq  = (short*)(ws + 67108864);      // 32 MiB  [4096][4096]
    short* Ck  = (short*)(ws + 100663296);     // 32 MiB  [4096][4096]
    short* Vt  = (short*)(ws + 134217728);     // 16 MiB  [2][16][128][2048]
    float* AO  = (float*)(ws + 16777216);      // 32 MiB, overlays Wqt+Wkt (dead by then)
    short* Nrm = (short*)(ws);                 // 16 MiB, overlays Xb (dead by then)

    cvt_bf16<<<8192, 256, 0, stream>>>(x, Xb);
    tposew<<<dim3(128, 64), 256, 0, stream>>>(Wq, Wqt, 2048, 4096);
    tposew<<<dim3(128, 64), 256, 0, stream>>>(Wk, Wkt, 2048, 4096);
    tposew<<<dim3(64, 64), 256, 0, stream>>>(Wv, Wvt, 2048, 2048);
    tposew<<<dim3(64, 64), 256, 0, stream>>>(Wo, Wot, 2048, 2048);

    gemm_bt<0><<<dim3(32, 32), 256, 0, stream>>>(Xb, Wqt, (void*)Cq, 4096, 4096, 2048);
    gemm_bt<0><<<dim3(32, 32), 256, 0, stream>>>(Xb, Wkt, (void*)Ck, 4096, 4096, 2048);
    gemm_bt<2><<<dim3(16, 32), 256, 0, stream>>>(Xb, Wvt, (void*)Vt, 4096, 2048, 2048);

    attn_kernel<<<dim3(1024), 256, 0, stream>>>(Cq, Ck, Vt, lam, AO);
    rms_kernel<<<4096, 256, 0, stream>>>(AO, nsc, lam, Nrm);
    gemm_bt<1><<<dim3(16, 32), 256, 0, stream>>>(Nrm, Wot, (void*)out, 4096, 2048, 2048);
}

// Round 3
// 600.073 us; speedup vs baseline: 1.2829x; 1.2829x over previous
//
#include <hip/hip_runtime.h>
#include <hip/hip_bf16.h>
#include <cstdint>
#include <cstddef>

typedef __attribute__((ext_vector_type(8))) short short8;
typedef __attribute__((ext_vector_type(4))) short short4v;
typedef __attribute__((ext_vector_type(4))) float float4v;

#define S_LEN 2048
#define NHEADS 16
#define DHEAD 128

__device__ __forceinline__ short f2bf(float f) {
    union { float f; unsigned u; } v; v.f = f;
    unsigned r = (v.u + 0x7fffu + ((v.u >> 16) & 1u)) >> 16;
    return (short)(r & 0xffffu);
}
// round-half-up bf16 pack: 2 VALU ops, error <= 1 ulp vs RNE
__device__ __forceinline__ short f2bf_rhu(float f) {
    union { float f; unsigned u; } v; v.f = f;
    return (short)((v.u + 0x8000u) >> 16);
}

typedef __attribute__((address_space(1))) void gvoid;
typedef __attribute__((address_space(3))) void lvoid;

__device__ __forceinline__ void gl_lds16(const void* g, void* l) {
    __builtin_amdgcn_global_load_lds((gvoid*)g, (lvoid*)l, 16, 0, 0);
}

__device__ __forceinline__ float4v mfma16(short8 a, short8 b, float4v c) {
    return __builtin_amdgcn_mfma_f32_16x16x32_bf16(a, b, c, 0, 0, 0);
}

// swizzled LDS tile addressing: tiles are arrays of 16B chunks.
__device__ __forceinline__ const char* lds8(const short* base, int row, int ch) {
    return (const char*)base + (((row << 3) + (ch ^ (row & 7))) << 4);
}
__device__ __forceinline__ const char* lds16a(const short* base, int row, int ch) {
    return (const char*)base + (((row << 4) + (ch ^ (row & 15))) << 4);
}

// ---------------- elementwise fp32 -> bf16 ----------------
__global__ __launch_bounds__(256)
void cvt_bf16(const float* __restrict__ X, short* __restrict__ Y) {
    size_t i = ((size_t)blockIdx.x * 256 + threadIdx.x) * 4;
    float4v v = *(const float4v*)(X + i);
    short4v o;
#pragma unroll
    for (int j = 0; j < 4; ++j) o[j] = f2bf(v[j]);
    *(short4v*)(Y + i) = o;
}

// ---------------- W[K][N] fp32 -> Wt[N][K] bf16, optional pre-scale ----------------
__global__ __launch_bounds__(256)
void tposew(const float* __restrict__ W, short* __restrict__ Wt, int K, int N, float scale) {
    __shared__ float t[32][33];
    int bx = blockIdx.x, by = blockIdx.y;
    int tx = threadIdx.x & 31, ty = threadIdx.x >> 5;
#pragma unroll
    for (int i = 0; i < 32; i += 8)
        t[ty + i][tx] = W[(size_t)(by * 32 + ty + i) * N + bx * 32 + tx];
    __syncthreads();
#pragma unroll
    for (int i = 0; i < 32; i += 8)
        Wt[(size_t)(bx * 32 + ty + i) * K + by * 32 + tx] = f2bf(t[tx][ty + i] * scale);
}

// ---------------- BT-GEMM: C[M][N] = A[M][K] * Bt[N][K]^T (bf16 in, f32 acc) ----
// MODE 0: store bf16 row-major; MODE 1: store f32 row-major;
// MODE 2: store bf16 scattered as Vt[b][n][s] (n = h*128+dh), i.e. ((b*2048+n)*2048 + s)
template <int MODE>
__global__ __launch_bounds__(256, 2)
void gemm_bt(const short* __restrict__ A, const short* __restrict__ Bt,
             void* __restrict__ Cv, int M, int N, int K) {
    __shared__ short sA[128 * 64];
    __shared__ short sB[128 * 64];
    const int tid = threadIdx.x;
    const int wid = tid >> 6, lane = tid & 63;
    const int quad = lane >> 4, l15 = lane & 15;
    const int n0 = blockIdx.x * 128, m0 = blockIdx.y * 128;
    const int wm = (wid & 1) * 64, wn = (wid >> 1) * 64;
    float4v acc[4][4] = {};
    for (int k0 = 0; k0 < K; k0 += 64) {
        __syncthreads();
#pragma unroll
        for (int i = 0; i < 4; ++i) {
            int c = i * 256 + tid;
            int row = c >> 3, kc = c & 7, g = kc ^ (row & 7);
            int lb = ((i << 8) + (wid << 6)) << 4;
            gl_lds16(A + (size_t)(m0 + row) * K + k0 + g * 8, (char*)(void*)sA + lb);
            gl_lds16(Bt + (size_t)(n0 + row) * K + k0 + g * 8, (char*)(void*)sB + lb);
        }
        __syncthreads();
#pragma unroll
        for (int ks = 0; ks < 2; ++ks) {
            short8 af[4], bf[4];
#pragma unroll
            for (int t = 0; t < 4; ++t) {
                int q = ks * 4 + quad;
                af[t] = *(const short8*)lds8(sA, wm + t * 16 + l15, q);
                bf[t] = *(const short8*)lds8(sB, wn + t * 16 + l15, q);
            }
#pragma unroll
            for (int mt = 0; mt < 4; ++mt)
#pragma unroll
                for (int nt = 0; nt < 4; ++nt)
                    acc[mt][nt] = mfma16(af[mt], bf[nt], acc[mt][nt]);
        }
    }
#pragma unroll
    for (int mt = 0; mt < 4; ++mt)
#pragma unroll
        for (int nt = 0; nt < 4; ++nt) {
            int rbase = m0 + wm + mt * 16 + quad * 4;
            int col = n0 + wn + nt * 16 + l15;
            if (MODE == 0) {
                short* Cb = (short*)Cv;
#pragma unroll
                for (int i = 0; i < 4; ++i)
                    Cb[(size_t)(rbase + i) * N + col] = f2bf(acc[mt][nt][i]);
            } else if (MODE == 1) {
                float* Cf = (float*)Cv;
#pragma unroll
                for (int i = 0; i < 4; ++i)
                    Cf[(size_t)(rbase + i) * N + col] = acc[mt][nt][i];
            } else {
                short4v pk;
#pragma unroll
                for (int i = 0; i < 4; ++i) pk[i] = f2bf(acc[mt][nt][i]);
                int bb = rbase >> 11, s = rbase & 2047;
                short* Cb = (short*)Cv;
                *(short4v*)(Cb + ((size_t)(bb * 2048 + col) * 2048 + s)) = pk;
            }
        }
}

// ---------------- fused differential attention (v3) ----------------
// Q pre-scaled by (1/sqrt(128))*log2(e) via Wq fold, so scores come out of the
// MFMA already in log2-domain: t = exp2(s) is the natural-exp of the scaled score.
// Pass 2 folds normalizers into exp args: t1/l1*log2e = exp2(s1 + c1).
// Q,Kq: bf16 [4096][4096] (col = h*256 + split*128 + dh)
// Vt:   bf16 [B][NH][DH][S];  AO: f32 [4096][2048]
__global__ __launch_bounds__(256, 2)
void attn_kernel(const short* __restrict__ Q, const short* __restrict__ Kq,
                 const short* __restrict__ Vt, const float* __restrict__ lam,
                 float* __restrict__ AO) {
    __shared__ short sK1[64 * 128];   // 16 KB
    __shared__ short sK2[64 * 128];   // 16 KB
    __shared__ short sV[128 * 64];    // 16 KB
    __shared__ short sP[4][32 * 64];  // 16 KB (4 KB/wave)

    const int tid = threadIdx.x;
    const int wid = tid >> 6, lane = tid & 63;
    const int quad = lane >> 4, l15 = lane & 15;

    // XCD swizzle: 4 consecutive bh per XCD (assumes round-robin linear-id->XCD;
    // perf heuristic only, correctness-independent)
    const int xb = blockIdx.x;
    const int local = xb >> 3;
    const int bh = (xb & 7) * 4 + (local >> 4);
    const int qx = local & 15;
    const int b = bh >> 4, h = bh & 15;
    const int wrow = qx * 128 + wid * 32;

    const float lamh = lam[h];
    const float C0 = 0.5287663729448977f;  // log2(log2(e))

    short8 q1f[2][4], q2f[2][4];
    {
        const short* qb = Q + (size_t)(b * S_LEN + wrow) * 4096 + h * 256;
#pragma unroll
        for (int mt = 0; mt < 2; ++mt)
#pragma unroll
            for (int ks = 0; ks < 4; ++ks) {
                const short* p = qb + (size_t)(mt * 16 + l15) * 4096 + ks * 32 + quad * 8;
                q1f[mt][ks] = *(const short8*)p;
                q2f[mt][ks] = *(const short8*)(p + 128);
            }
    }
    const short* k1g = Kq + (size_t)(b * S_LEN) * 4096 + h * 256;
    const short* k2g = k1g + 128;
    const short* vg = Vt + (size_t)(b * NHEADS + h) * DHEAD * S_LEN;

    int offK[4], offV[4], lbs[4];
#pragma unroll
    for (int i = 0; i < 4; ++i) {
        int c = i * 256 + tid;
        int row = c >> 4, kc = c & 15;
        offK[i] = row * 4096 + ((kc ^ (row & 15)) << 3);
        int dh = c >> 3, vc = c & 7;
        offV[i] = dh * 2048 + ((vc ^ (dh & 7)) << 3);
        lbs[i] = ((i << 8) + (wid << 6)) << 4;
    }

    float l1a[2][4] = {}, l2a[2][4] = {};

    // ---- pass 1: l1 = sum exp2(s1), l2 = sum exp2(s2); no max needed (|s| small)
    for (int kt = 0; kt < S_LEN; kt += 64) {
        const short* k1b = k1g + (size_t)kt * 4096;
        const short* k2b = k2g + (size_t)kt * 4096;
        __syncthreads();
#pragma unroll
        for (int i = 0; i < 4; ++i) {
            gl_lds16(k1b + offK[i], (char*)(void*)sK1 + lbs[i]);
            gl_lds16(k2b + offK[i], (char*)(void*)sK2 + lbs[i]);
        }
        __syncthreads();
#pragma unroll
        for (int nt = 0; nt < 4; ++nt) {
            float4v s1[2] = {}, s2[2] = {};
            int krow = nt * 16 + l15;
#pragma unroll
            for (int ks = 0; ks < 4; ++ks) {
                int q = ks * 4 + quad;
                short8 kb1 = *(const short8*)lds16a(sK1, krow, q);
                short8 kb2 = *(const short8*)lds16a(sK2, krow, q);
#pragma unroll
                for (int mt = 0; mt < 2; ++mt) {
                    s1[mt] = mfma16(q1f[mt][ks], kb1, s1[mt]);
                    s2[mt] = mfma16(q2f[mt][ks], kb2, s2[mt]);
                }
            }
#pragma unroll
            for (int mt = 0; mt < 2; ++mt)
#pragma unroll
                for (int r = 0; r < 4; ++r) {
                    l1a[mt][r] += __builtin_amdgcn_exp2f(s1[mt][r]);
                    l2a[mt][r] += __builtin_amdgcn_exp2f(s2[mt][r]);
                }
        }
    }
#pragma unroll
    for (int off = 1; off < 16; off <<= 1)
#pragma unroll
        for (int mt = 0; mt < 2; ++mt)
#pragma unroll
            for (int r = 0; r < 4; ++r) {
                l1a[mt][r] += __shfl_xor(l1a[mt][r], off, 64);
                l2a[mt][r] += __shfl_xor(l2a[mt][r], off, 64);
            }
    // fold normalizers into exp2 args: t1/l1*log2e = exp2(s1 + c1)
    const float llam = __log2f(lamh);
    float c1[2][4], c2[2][4];
#pragma unroll
    for (int mt = 0; mt < 2; ++mt)
#pragma unroll
        for (int r = 0; r < 4; ++r) {
            c1[mt][r] = C0 - __log2f(l1a[mt][r]);
            c2[mt][r] = C0 + llam - __log2f(l2a[mt][r]);
        }

    float lda[2][4] = {};
    float4v oacc[2][8] = {};

    // ---- pass 2: e = exp2(exp2(s1+c1) - exp2(s2+c2)); O += P@V
    for (int kt = 0; kt < S_LEN; kt += 64) {
        const short* k1b = k1g + (size_t)kt * 4096;
        const short* k2b = k2g + (size_t)kt * 4096;
        const short* vb = vg + kt;
        __syncthreads();
#pragma unroll
        for (int i = 0; i < 4; ++i) {
            gl_lds16(k1b + offK[i], (char*)(void*)sK1 + lbs[i]);
            gl_lds16(k2b + offK[i], (char*)(void*)sK2 + lbs[i]);
            gl_lds16(vb + offV[i], (char*)(void*)sV + lbs[i]);
        }
        __syncthreads();
        short* sPw = sP[wid];
#pragma unroll
        for (int nt = 0; nt < 4; ++nt) {
            float4v s1[2] = {}, s2[2] = {};
            int krow = nt * 16 + l15;
#pragma unroll
            for (int ks = 0; ks < 4; ++ks) {
                int q = ks * 4 + quad;
                short8 kb1 = *(const short8*)lds16a(sK1, krow, q);
                short8 kb2 = *(const short8*)lds16a(sK2, krow, q);
#pragma unroll
                for (int mt = 0; mt < 2; ++mt) {
                    s1[mt] = mfma16(q1f[mt][ks], kb1, s1[mt]);
                    s2[mt] = mfma16(q2f[mt][ks], kb2, s2[mt]);
                }
            }
#pragma unroll
            for (int mt = 0; mt < 2; ++mt)
#pragma unroll
                for (int r = 0; r < 4; ++r) {
                    float u1 = __builtin_amdgcn_exp2f(s1[mt][r] + c1[mt][r]);
                    float u2 = __builtin_amdgcn_exp2f(s2[mt][r] + c2[mt][r]);
                    float e = __builtin_amdgcn_exp2f(u1 - u2);
                    lda[mt][r] += e;
                    int qrow = mt * 16 + quad * 4 + r;
                    int key = nt * 16 + l15;
                    *(short*)((char*)sPw +
                              ((((qrow << 3) + ((key >> 3) ^ (qrow & 7))) << 4) +
                               ((key & 7) << 1))) = f2bf_rhu(e);
                }
        }
        // PV: sP is wave-private (per-wave lgkm ordering suffices, no barrier);
        // sV protected by loop-top + post-load barriers
#pragma unroll
        for (int kk = 0; kk < 2; ++kk) {
            short8 pa[2];
#pragma unroll
            for (int mt = 0; mt < 2; ++mt)
                pa[mt] = *(const short8*)lds8(sPw, mt * 16 + l15, kk * 4 + quad);
#pragma unroll
            for (int nt = 0; nt < 8; ++nt) {
                short8 vbf = *(const short8*)lds8(sV, nt * 16 + l15, kk * 4 + quad);
#pragma unroll
                for (int mt = 0; mt < 2; ++mt)
                    oacc[mt][nt] = mfma16(pa[mt], vbf, oacc[mt][nt]);
            }
        }
    }
#pragma unroll
    for (int off = 1; off < 16; off <<= 1)
#pragma unroll
        for (int mt = 0; mt < 2; ++mt)
#pragma unroll
            for (int r = 0; r < 4; ++r)
                lda[mt][r] += __shfl_xor(lda[mt][r], off, 64);
#pragma unroll
    for (int mt = 0; mt < 2; ++mt) {
        float ild[4];
#pragma unroll
        for (int r = 0; r < 4; ++r) ild[r] = 1.0f / lda[mt][r];
#pragma unroll
        for (int nt = 0; nt < 8; ++nt)
#pragma unroll
            for (int r = 0; r < 4; ++r) {
                int row = b * S_LEN + wrow + mt * 16 + quad * 4 + r;
                int col = h * DHEAD + nt * 16 + l15;
                AO[(size_t)row * 2048 + col] = oacc[mt][nt][r] * ild[r];
            }
    }
}

// ---------------- RMS norm + scale * (1 - mean(lam)), f32 -> bf16 ----------------
__global__ __launch_bounds__(256)
void rms_kernel(const float* __restrict__ AO, const float* __restrict__ gs,
                const float* __restrict__ lam, short* __restrict__ Y) {
    int row = blockIdx.x, tid = threadIdx.x;
    const float* x = AO + (size_t)row * 2048;
    float4v v0 = *(const float4v*)(x + tid * 8);
    float4v v1 = *(const float4v*)(x + tid * 8 + 4);
    float ss = 0;
#pragma unroll
    for (int j = 0; j < 4; ++j) ss += v0[j] * v0[j] + v1[j] * v1[j];
#pragma unroll
    for (int off = 32; off > 0; off >>= 1) ss += __shfl_xor(ss, off, 64);
    __shared__ float wsum[4];
    if ((tid & 63) == 0) wsum[tid >> 6] = ss;
    __syncthreads();
    float tot = wsum[0] + wsum[1] + wsum[2] + wsum[3];
    float lm = 0;
#pragma unroll
    for (int i = 0; i < 16; ++i) lm += lam[i];
    float f = (1.0f - lm * (1.0f / 16.0f)) * rsqrtf(tot * (1.0f / 2048.0f) + 1e-6f);
    float4v g0 = *(const float4v*)(gs + tid * 8);
    float4v g1 = *(const float4v*)(gs + tid * 8 + 4);
    short4v o0, o1;
#pragma unroll
    for (int j = 0; j < 4; ++j) {
        o0[j] = f2bf(v0[j] * f * g0[j]);
        o1[j] = f2bf(v1[j] * f * g1[j]);
    }
    *(short4v*)(Y + (size_t)row * 2048 + tid * 8) = o0;
    *(short4v*)(Y + (size_t)row * 2048 + tid * 8 + 4) = o1;
}

extern "C" void kernel_launch(void* const* d_in, const int* in_sizes, int n_in,
                              void* d_out, int out_size, void* d_ws, size_t ws_size,
                              hipStream_t stream) {
    const float* x = (const float*)d_in[0];
    const float* Wq = (const float*)d_in[1];
    const float* Wk = (const float*)d_in[2];
    const float* Wv = (const float*)d_in[3];
    const float* Wo = (const float*)d_in[4];
    const float* nsc = (const float*)d_in[5];
    const float* lam = (const float*)d_in[6];
    float* out = (float*)d_out;
    (void)in_sizes; (void)n_in; (void)out_size; (void)ws_size;

    char* ws = (char*)d_ws;
    short* Xb  = (short*)(ws);                 // 16 MiB  [4096][2048]
    short* Wqt = (short*)(ws + 16777216);      // 16 MiB  [4096][2048]
    short* Wkt = (short*)(ws + 33554432);      // 16 MiB  [4096][2048]
    short* Wvt = (short*)(ws + 50331648);      //  8 MiB  [2048][2048]
    short* Wot = (short*)(ws + 58720256);      //  8 MiB  [2048][2048]
    short* Cq  = (short*)(ws + 67108864);      // 32 MiB  [4096][4096]
    short* Ck  = (short*)(ws + 100663296);     // 32 MiB  [4096][4096]
    short* Vt  = (short*)(ws + 134217728);     // 16 MiB  [2][16][128][2048]
    float* AO  = (float*)(ws + 16777216);      // 32 MiB, overlays Wqt+Wkt (dead by then)
    short* Nrm = (short*)(ws);                 // 16 MiB, overlays Xb (dead by then)

    // QKSCALE = (1/sqrt(128)) * log2(e), folded into Wq so scores exit the MFMA
    // in log2-domain
    const float QKSCALE = 0.12752965213246994f;

    cvt_bf16<<<8192, 256, 0, stream>>>(x, Xb);
    tposew<<<dim3(128, 64), 256, 0, stream>>>(Wq, Wqt, 2048, 4096, QKSCALE);
    tposew<<<dim3(128, 64), 256, 0, stream>>>(Wk, Wkt, 2048, 4096, 1.0f);
    tposew<<<dim3(64, 64), 256, 0, stream>>>(Wv, Wvt, 2048, 2048, 1.0f);
    tposew<<<dim3(64, 64), 256, 0, stream>>>(Wo, Wot, 2048, 2048, 1.0f);

    gemm_bt<0><<<dim3(32, 32), 256, 0, stream>>>(Xb, Wqt, (void*)Cq, 4096, 4096, 2048);
    gemm_bt<0><<<dim3(32, 32), 256, 0, stream>>>(Xb, Wkt, (void*)Ck, 4096, 4096, 2048);
    gemm_bt<2><<<dim3(16, 32), 256, 0, stream>>>(Xb, Wvt, (void*)Vt, 4096, 2048, 2048);

    attn_kernel<<<dim3(512), 256, 0, stream>>>(Cq, Ck, Vt, lam, AO);
    rms_kernel<<<4096, 256, 0, stream>>>(AO, nsc, lam, Nrm);
    gemm_bt<1><<<dim3(16, 32), 256, 0, stream>>>(Nrm, Wot, (void*)out, 4096, 2048, 2048);
}